// Round 11
// baseline (936.905 us; speedup 1.0000x reference)
//
#include <hip/hip_runtime.h>
#include <cstdio>

// MoE top-2 FFN: B=4,S=2048,D=1024 -> T=8192 tokens; E=8, H=4096, K_TOP=2.
// Round 11: consolidation. Exact r2 GEMM loop (best measured: 270us/GEMM) —
// plain __launch_bounds__(256) (VGPR ~76; (256,6) spills, (256,4)'s 56-VGPR
// cap serializes ds_reads), no swizzle, BK=32, 16KB LDS, row-fast XCD grid.
// Plus proven-pure wins: pad-tile skip, 128-pad (MAXR 17408), atomic GEMM2
// epilogue (no ybuf/combine), ILP-8 LDS-free weight transpose.

#define T_TOK 8192
#define DIM   1024
#define NEXP  8
#define HID   4096
#define MAXR  17408  // 16384 rows + 8 experts * up-to-127 pad, mult of 128

typedef float          f32x4   __attribute__((ext_vector_type(4)));
typedef short          bf16x8  __attribute__((ext_vector_type(8)));
typedef unsigned short u16x8   __attribute__((ext_vector_type(8)));
typedef unsigned short u16x4   __attribute__((ext_vector_type(4)));

static __device__ __forceinline__ unsigned short f2bf(float f) {
  unsigned int u = __builtin_bit_cast(unsigned int, f);
  u = (u + 0x7FFFu + ((u >> 16) & 1u)) >> 16;   // round-nearest-even (finite inputs)
  return (unsigned short)u;
}

// async global->LDS, 16B per lane; LDS dest = wave-uniform base + lane*16
static __device__ __forceinline__ void gl16(const void* g, void* l) {
  __builtin_amdgcn_global_load_lds(
      (const __attribute__((address_space(1))) unsigned int*)g,
      (__attribute__((address_space(3))) unsigned int*)l,
      16, 0, 0);
}

// ---------------- transpose + fp32->bf16, LDS-free, ILP=8 --------------------
// W[e][R][C] fp32 -> WT[e][C][R] bf16.  Block = 64 rows x 128 cols, 4 waves
// (wave w: cols w*32..w*32+31).  Lane: r8=(lane&7)*8 rows, cg=lane>>3 col-grp.
// Loads: 8x float4 (row-strided).  Stores: 4x u16x8 (128B-contiguous runs).
static __device__ __forceinline__ void transpose_body(const float* __restrict__ W,
                                                      unsigned short* __restrict__ WT,
                                                      int R, int C, int bx, int by, int e) {
  int lane = threadIdx.x & 63, w = threadIdx.x >> 6;
  int r0 = by * 64, c0 = bx * 128 + w * 32;
  int r8 = (lane & 7) * 8, cg = lane >> 3;
  const float* src = W + (size_t)e * R * C + (size_t)(r0 + r8) * C + c0 + cg * 4;
  float4 v[8];
#pragma unroll
  for (int j = 0; j < 8; ++j) v[j] = *(const float4*)(src + (size_t)j * C);
  unsigned short* dst = WT + (size_t)e * R * C + (size_t)(c0 + cg * 4) * R + r0 + r8;
#pragma unroll
  for (int s = 0; s < 4; ++s) {
    u16x8 o;
#pragma unroll
    for (int j = 0; j < 8; ++j) {
      float f = s == 0 ? v[j].x : s == 1 ? v[j].y : s == 2 ? v[j].z : v[j].w;
      o[j] = f2bf(f);
    }
    *(u16x8*)(dst + (size_t)s * R) = o;
  }
}

static __device__ __forceinline__ void router_body(int blk, const float* __restrict__ x,
                                                   const float* __restrict__ Wr,
                                                   const float* __restrict__ br,
                                                   int* __restrict__ meta,
                                                   int2* __restrict__ top_i,
                                                   float2* __restrict__ top_w) {
  int lane = threadIdx.x & 63;
  int wid  = threadIdx.x >> 6;
  int t = blk * 4 + wid;
  const float* xp = x + (size_t)t * DIM + lane * 16;
  float acc[NEXP];
#pragma unroll
  for (int e = 0; e < NEXP; ++e) acc[e] = 0.f;
#pragma unroll
  for (int j = 0; j < 16; j += 4) {
    float4 xv = *(const float4*)(xp + j);
    const float* wp = Wr + (size_t)(lane * 16 + j) * NEXP;
#pragma unroll
    for (int jj = 0; jj < 4; ++jj) {
      float xs = jj == 0 ? xv.x : jj == 1 ? xv.y : jj == 2 ? xv.z : xv.w;
      float4 w0 = *(const float4*)(wp + jj * NEXP);
      float4 w1 = *(const float4*)(wp + jj * NEXP + 4);
      acc[0] += xs * w0.x; acc[1] += xs * w0.y; acc[2] += xs * w0.z; acc[3] += xs * w0.w;
      acc[4] += xs * w1.x; acc[5] += xs * w1.y; acc[6] += xs * w1.z; acc[7] += xs * w1.w;
    }
  }
#pragma unroll
  for (int off = 32; off > 0; off >>= 1) {
#pragma unroll
    for (int e = 0; e < NEXP; ++e) acc[e] += __shfl_xor(acc[e], off);
  }
  if (lane == 0) {
    float l[NEXP];
#pragma unroll
    for (int e = 0; e < NEXP; ++e) l[e] = acc[e] + br[e];
    int e1 = 0;
#pragma unroll
    for (int e = 1; e < NEXP; ++e) if (l[e] > l[e1]) e1 = e;      // ties -> lower idx
    int e2 = (e1 == 0) ? 1 : 0;
#pragma unroll
    for (int e = 0; e < NEXP; ++e) if (e != e1 && l[e] > l[e2]) e2 = e;
    float g  = expf(l[e2] - l[e1]);              // softmax over top-2 == renorm of full softmax
    float w1 = 1.f / (1.f + g);
    top_i[t] = make_int2(e1, e2);
    top_w[t] = make_float2(w1, 1.f - w1);
    atomicAdd(&meta[e1], 1);
    atomicAdd(&meta[e2], 1);
  }
}

// ---- fused prep: [0,4096) W1 transpose, [4096,8192) W2 transpose,
//      [8192,10240) router, [10240,10308) fill pad-row arrays ----------------
__global__ __launch_bounds__(256) void prep_k(const float* __restrict__ W1,
                                              const float* __restrict__ W2,
                                              unsigned short* __restrict__ W1bT,
                                              unsigned short* __restrict__ W2bT,
                                              const float* __restrict__ x,
                                              const float* __restrict__ Wr,
                                              const float* __restrict__ br,
                                              int* __restrict__ meta,
                                              int2* __restrict__ top_i,
                                              float2* __restrict__ top_w,
                                              int* __restrict__ tok_of_row,
                                              float* __restrict__ wt_of_row) {
  int id = blockIdx.x;
  if (id < 4096) {                               // W1[e][D][H] -> [e][H][D]
    int rem = id & 511;                          // 16 by x 32 bx per expert
    transpose_body(W1, W1bT, DIM, HID, rem & 31, rem >> 5, id >> 9);
  } else if (id < 8192) {                        // W2[e][H][D] -> [e][D][H]
    int id2 = id - 4096;
    int rem = id2 & 511;                         // 64 by x 8 bx per expert
    transpose_body(W2, W2bT, HID, DIM, rem & 7, rem >> 3, id2 >> 9);
  } else if (id < 10240) {
    router_body(id - 8192, x, Wr, br, meta, top_i, top_w);
  } else {
    int i = (id - 10240) * 256 + threadIdx.x;    // 68*256 == MAXR exactly
    if (i < MAXR) { tok_of_row[i] = 0; wt_of_row[i] = 0.f; }
  }
}

// -------- prefix: padded (x128) offsets ------------------------------------
__global__ void prefix_k(int* __restrict__ meta) {
  if (threadIdx.x == 0) {
    int s = 0;
#pragma unroll
    for (int e = 0; e < NEXP; ++e) {
      meta[16 + e] = s;                          // poff[e]
      s += (meta[e] + 127) & ~127;
    }
    meta[24] = s;                                // poff[8]
    meta[25] = s;                                // total_padded (<= MAXR always)
  }
}

// ---------------- scatter: token -> packed expert row ------------------------
__global__ __launch_bounds__(256) void scatter_k(const int2* __restrict__ top_i,
                                                 const float2* __restrict__ top_w,
                                                 int* __restrict__ meta,
                                                 int* __restrict__ row_of,
                                                 int* __restrict__ tok_of_row,
                                                 float* __restrict__ wt_of_row) {
  int t = blockIdx.x * 256 + threadIdx.x;
  int2  ei = top_i[t];
  float2 w = top_w[t];
  int p = atomicAdd(&meta[8 + ei.x], 1);
  int r = meta[16 + ei.x] + p;
  tok_of_row[r] = t; wt_of_row[r] = w.x; row_of[t * 2] = r;
  p = atomicAdd(&meta[8 + ei.y], 1);
  r = meta[16 + ei.y] + p;
  tok_of_row[r] = t; wt_of_row[r] = w.y; row_of[t * 2 + 1] = r;
}

// ---------------- gather: xg[r][:] = bf16(x[tok[r]][:]) ----------------------
__global__ __launch_bounds__(256) void gather_k(const float* __restrict__ x,
                                                const int* __restrict__ tok_of_row,
                                                const int* __restrict__ meta,
                                                unsigned short* __restrict__ xg) {
  int r = blockIdx.x;
  if (r >= meta[25]) return;
  int t = tok_of_row[r];
  int c = threadIdx.x * 4;
  float4 v = *(const float4*)(x + (size_t)t * DIM + c);
  u16x4 o;
  o[0] = f2bf(v.x); o[1] = f2bf(v.y); o[2] = f2bf(v.z); o[3] = f2bf(v.w);
  *(u16x4*)(xg + (size_t)r * DIM + c) = o;
}

// ---------------- grouped GEMM: exact r2 loop + pad-skip ---------------------
// A: [M][KTOT] bf16 packed rows.  Bt: [E][NTOT][KTOT] bf16 (pre-transposed).
// 128x128 tile, BK=32, 4 waves (2x2), 16KB LDS, linear layout (no swizzle).
// Per K-tile: sync; 4x gl16; sync; 8x ds_read_b128; 16x mfma_16x16x32_bf16.
// Grid: XCD-chunked, row-fast within chunk (r2-proven: B-panel L2 reuse).
// EPI 0: h = bf16(gelu(acc+b1))   EPI 1: atomicAdd out[tok] += (acc+b2)*wt
// NOTE: no min-waves in launch_bounds — (256,6) spilled acc (r7/r9, 2.3GB
// scratch writes); (256,4)'s 56-VGPR cap serialized ds_reads (r10, +16%).

template <int KTOT, int NTOT, int EPI>
__global__ __launch_bounds__(256) void gemmv11_k(const unsigned short* __restrict__ A,
                                                 const unsigned short* __restrict__ Bt,
                                                 const float* __restrict__ bias,
                                                 const int* __restrict__ meta,
                                                 const float* __restrict__ wt_of_row,
                                                 const int* __restrict__ tok_of_row,
                                                 void* __restrict__ Cout) {
  constexpr int NXB = MAXR / 128;                // 136 row tiles
  constexpr int NWG = NXB * (NTOT / 128);        // 4352 or 1088, both % 8 == 0
  constexpr int NKT = KTOT / 32;
  __shared__ __align__(16) unsigned short lds[8192];   // 16 KiB

  // XCD-chunked, row-fast within chunk: consecutive ids share n0 (B-panel hot)
  int id = ((int)blockIdx.x & 7) * (NWG / 8) + ((int)blockIdx.x >> 3);
  int row0 = (id % NXB) * 128;
  int n0   = (id / NXB) * 128;
  if (row0 >= meta[25]) return;                  // beyond padded total (block-uniform)
  int e = 0;
  while (meta[17 + e] <= row0) ++e;              // tiles never straddle experts
  if (row0 - meta[16 + e] >= meta[e]) return;    // all-pad tile: skip (wt==0 gates EPI1;
                                                 // unwritten hbuf rows are finite garbage
                                                 // multiplied by wt==0 in GEMM2)
  const unsigned short* Bp = Bt + (size_t)e * NTOT * KTOT;

  int tid = threadIdx.x;
  int lane = tid & 63, wid = tid >> 6;
  int wm = wid >> 1, wn = wid & 1;               // 2x2 waves, each owns 64x64 of C
  int rs = tid >> 2;                             // staging row 0..63
  int cs = (tid & 3) * 8;                        // staging col (ushorts)

  const unsigned short* Ag = A  + (size_t)(row0 + rs) * KTOT + cs;
  const unsigned short* Bg = Bp + (size_t)(n0   + rs) * KTOT + cs;
  unsigned short* Al = lds + tid * 8;            // linear: row*32 + col == tid*8
  unsigned short* Bl = lds + 4096 + tid * 8;

  f32x4 acc[4][4];
#pragma unroll
  for (int i = 0; i < 4; ++i)
#pragma unroll
    for (int j = 0; j < 4; ++j) acc[i][j] = (f32x4){0.f, 0.f, 0.f, 0.f};

  int am = lane & 15, ak = (lane >> 4) * 8;      // frag: m/n = lane&15, k = (lane>>4)*8 + j

  for (int kt = 0; kt < KTOT; kt += 32) {
    __syncthreads();                             // prev compute done before overwrite
    gl16(Ag + kt, Al);
    gl16(Ag + 64 * KTOT + kt, Al + 2048);        // rows 64..127
    gl16(Bg + kt, Bl);
    gl16(Bg + 64 * KTOT + kt, Bl + 2048);
    __syncthreads();                             // compiler drains vmcnt before barrier
    bf16x8 af[4], bv[4];
#pragma unroll
    for (int i = 0; i < 4; ++i)
      af[i] = *(const bf16x8*)(lds + (wm * 64 + i * 16 + am) * 32 + ak);
#pragma unroll
    for (int j = 0; j < 4; ++j)
      bv[j] = *(const bf16x8*)(lds + 4096 + (wn * 64 + j * 16 + am) * 32 + ak);
#pragma unroll
    for (int i = 0; i < 4; ++i)
#pragma unroll
      for (int j = 0; j < 4; ++j)
        acc[i][j] = __builtin_amdgcn_mfma_f32_16x16x32_bf16(af[i], bv[j], acc[i][j], 0, 0, 0);
  }

  // epilogue.  C/D: col n = lane&15, row m = (lane>>4)*4 + reg  (validated)
  int rbase = row0 + wm * 64 + ((lane >> 4) << 2);
  int nbase = n0 + wn * 64 + am;
  if constexpr (EPI == 0) {
    unsigned short* Hp = (unsigned short*)Cout;
    const float* bp = bias + (size_t)e * NTOT;
#pragma unroll
    for (int i = 0; i < 4; ++i)
#pragma unroll
      for (int j = 0; j < 4; ++j) {
        int n = nbase + j * 16;
        float bv = bp[n];
#pragma unroll
        for (int g = 0; g < 4; ++g) {
          int m = rbase + i * 16 + g;
          float v = acc[i][j][g] + bv;
          v = 0.5f * v * (1.f + erff(v * 0.70710678118654752f));   // exact gelu
          Hp[(size_t)m * NTOT + n] = f2bf(v);
        }
      }
  } else {
    float* Op = (float*)Cout;
    const float* bp = bias + (size_t)e * NTOT;
#pragma unroll
    for (int i = 0; i < 4; ++i)
#pragma unroll
      for (int g = 0; g < 4; ++g) {
        int m = rbase + i * 16 + g;
        float wt = wt_of_row[m];
        if (wt != 0.f) {                         // pad rows excluded (wt exactly 0)
          float* orow = Op + (size_t)tok_of_row[m] * DIM;
#pragma unroll
          for (int j = 0; j < 4; ++j) {
            int n = nbase + j * 16;
            atomicAdd(orow + n, (acc[i][j][g] + bp[n]) * wt);
          }
        }
      }
  }
}

extern "C" void kernel_launch(void* const* d_in, const int* in_sizes, int n_in,
                              void* d_out, int out_size, void* d_ws, size_t ws_size,
                              hipStream_t stream) {
  const float* x  = (const float*)d_in[0];
  const float* Wr = (const float*)d_in[1];
  const float* br = (const float*)d_in[2];
  const float* W1 = (const float*)d_in[3];
  const float* b1 = (const float*)d_in[4];
  const float* W2 = (const float*)d_in[5];
  const float* b2 = (const float*)d_in[6];
  float* out = (float*)d_out;

  char* base = (char*)d_ws;
  size_t off = 0;
  auto carve = [&](size_t bytes) -> void* {
    void* r = base + off;
    off = (off + bytes + 255) & ~(size_t)255;
    return r;
  };
  int*            meta       = (int*)carve(26 * 4);
  int2*           top_i      = (int2*)carve((size_t)T_TOK * 8);
  float2*         top_w      = (float2*)carve((size_t)T_TOK * 8);
  int*            row_of     = (int*)carve((size_t)T_TOK * 2 * 4);
  int*            tok_of_row = (int*)carve((size_t)MAXR * 4);
  float*          wt_of_row  = (float*)carve((size_t)MAXR * 4);
  unsigned short* xg         = (unsigned short*)carve((size_t)MAXR * DIM * 2);
  unsigned short* W1bT       = (unsigned short*)carve((size_t)NEXP * DIM * HID * 2);
  unsigned short* W2bT       = (unsigned short*)carve((size_t)NEXP * DIM * HID * 2);
  unsigned short* hbuf       = (unsigned short*)carve((size_t)MAXR * HID * 2);
  if (off > ws_size) {
    fprintf(stderr, "kernel_launch: ws_size too small: need %zu have %zu\n", off, ws_size);
    return;
  }

  hipMemsetAsync(meta, 0, 26 * 4, stream);
  hipMemsetAsync(out, 0, (size_t)out_size * 4, stream);   // GEMM2 atomicAdds into out
  hipLaunchKernelGGL(prep_k, dim3(10308), dim3(256), 0, stream,
                     W1, W2, W1bT, W2bT, x, Wr, br, meta, top_i, top_w,
                     tok_of_row, wt_of_row);
  hipLaunchKernelGGL(prefix_k, dim3(1), dim3(64), 0, stream, meta);
  hipLaunchKernelGGL(scatter_k, dim3(T_TOK / 256), dim3(256), 0, stream,
                     top_i, top_w, meta, row_of, tok_of_row, wt_of_row);
  hipLaunchKernelGGL(gather_k, dim3(MAXR), dim3(256), 0, stream, x, tok_of_row, meta, xg);
  hipLaunchKernelGGL((gemmv11_k<DIM, HID, 0>), dim3((MAXR / 128) * (HID / 128)), dim3(256), 0,
                     stream, xg, W1bT, b1, meta, wt_of_row, tok_of_row, (void*)hbuf);
  hipLaunchKernelGGL((gemmv11_k<HID, DIM, 1>), dim3((MAXR / 128) * (DIM / 128)), dim3(256), 0,
                     stream, hbuf, W2bT, b2, meta, wt_of_row, tok_of_row, (void*)out);
}

// Round 12
// 814.713 us; speedup vs baseline: 1.1500x; 1.1500x over previous
//
#include <hip/hip_runtime.h>
#include <cstdio>

// MoE top-2 FFN: B=4,S=2048,D=1024 -> T=8192 tokens; E=8, H=4096, K_TOP=2.
// Round 12: r8's GEMM verbatim (BK=64, 32KB LDS, 8-slot XOR swizzle,
// launch_bounds(256,4), atomic GEMM2 epilogue; 286us/GEMM measured) + the
// de-confounded supertile grid (r10 proved FETCH 610->208MB but tainted it
// with a VGPR cap at BK=32): XCD owns a 4-n-tile supergroup (1MB B-panel
// L2-resident), walks 4-row supertiles. + pad-tile skip + ILP-8 prep (r9).

#define T_TOK 8192
#define DIM   1024
#define NEXP  8
#define HID   4096
#define MAXR  18432  // 16384 rows + 8 experts * up-to-255 pad, rounded to 256

typedef float          f32x4   __attribute__((ext_vector_type(4)));
typedef short          bf16x8  __attribute__((ext_vector_type(8)));
typedef unsigned short u16x8   __attribute__((ext_vector_type(8)));
typedef unsigned short u16x4   __attribute__((ext_vector_type(4)));

static __device__ __forceinline__ unsigned short f2bf(float f) {
  unsigned int u = __builtin_bit_cast(unsigned int, f);
  u = (u + 0x7FFFu + ((u >> 16) & 1u)) >> 16;   // round-nearest-even (finite inputs)
  return (unsigned short)u;
}

// async global->LDS, 16B per lane; LDS dest = wave-uniform base + lane*16
static __device__ __forceinline__ void gl16(const void* g, void* l) {
  __builtin_amdgcn_global_load_lds(
      (const __attribute__((address_space(1))) unsigned int*)g,
      (__attribute__((address_space(3))) unsigned int*)l,
      16, 0, 0);
}

// ---------------- transpose + fp32->bf16, LDS-free, ILP=8 --------------------
// W[e][R][C] fp32 -> WT[e][C][R] bf16.  Block = 64 rows x 128 cols, 4 waves.
static __device__ __forceinline__ void transpose_body(const float* __restrict__ W,
                                                      unsigned short* __restrict__ WT,
                                                      int R, int C, int bx, int by, int e) {
  int lane = threadIdx.x & 63, w = threadIdx.x >> 6;
  int r0 = by * 64, c0 = bx * 128 + w * 32;
  int r8 = (lane & 7) * 8, cg = lane >> 3;
  const float* src = W + (size_t)e * R * C + (size_t)(r0 + r8) * C + c0 + cg * 4;
  float4 v[8];
#pragma unroll
  for (int j = 0; j < 8; ++j) v[j] = *(const float4*)(src + (size_t)j * C);
  unsigned short* dst = WT + (size_t)e * R * C + (size_t)(c0 + cg * 4) * R + r0 + r8;
#pragma unroll
  for (int s = 0; s < 4; ++s) {
    u16x8 o;
#pragma unroll
    for (int j = 0; j < 8; ++j) {
      float f = s == 0 ? v[j].x : s == 1 ? v[j].y : s == 2 ? v[j].z : v[j].w;
      o[j] = f2bf(f);
    }
    *(u16x8*)(dst + (size_t)s * R) = o;
  }
}

static __device__ __forceinline__ void router_body(int blk, const float* __restrict__ x,
                                                   const float* __restrict__ Wr,
                                                   const float* __restrict__ br,
                                                   int* __restrict__ meta,
                                                   int2* __restrict__ top_i,
                                                   float2* __restrict__ top_w) {
  int lane = threadIdx.x & 63;
  int wid  = threadIdx.x >> 6;
  int t = blk * 4 + wid;
  const float* xp = x + (size_t)t * DIM + lane * 16;
  float acc[NEXP];
#pragma unroll
  for (int e = 0; e < NEXP; ++e) acc[e] = 0.f;
#pragma unroll
  for (int j = 0; j < 16; j += 4) {
    float4 xv = *(const float4*)(xp + j);
    const float* wp = Wr + (size_t)(lane * 16 + j) * NEXP;
#pragma unroll
    for (int jj = 0; jj < 4; ++jj) {
      float xs = jj == 0 ? xv.x : jj == 1 ? xv.y : jj == 2 ? xv.z : xv.w;
      float4 w0 = *(const float4*)(wp + jj * NEXP);
      float4 w1 = *(const float4*)(wp + jj * NEXP + 4);
      acc[0] += xs * w0.x; acc[1] += xs * w0.y; acc[2] += xs * w0.z; acc[3] += xs * w0.w;
      acc[4] += xs * w1.x; acc[5] += xs * w1.y; acc[6] += xs * w1.z; acc[7] += xs * w1.w;
    }
  }
#pragma unroll
  for (int off = 32; off > 0; off >>= 1) {
#pragma unroll
    for (int e = 0; e < NEXP; ++e) acc[e] += __shfl_xor(acc[e], off);
  }
  if (lane == 0) {
    float l[NEXP];
#pragma unroll
    for (int e = 0; e < NEXP; ++e) l[e] = acc[e] + br[e];
    int e1 = 0;
#pragma unroll
    for (int e = 1; e < NEXP; ++e) if (l[e] > l[e1]) e1 = e;      // ties -> lower idx
    int e2 = (e1 == 0) ? 1 : 0;
#pragma unroll
    for (int e = 0; e < NEXP; ++e) if (e != e1 && l[e] > l[e2]) e2 = e;
    float g  = expf(l[e2] - l[e1]);              // softmax over top-2 == renorm of full softmax
    float w1 = 1.f / (1.f + g);
    top_i[t] = make_int2(e1, e2);
    top_w[t] = make_float2(w1, 1.f - w1);
    atomicAdd(&meta[e1], 1);
    atomicAdd(&meta[e2], 1);
  }
}

// ---- fused prep: [0,4096) W1 transpose, [4096,8192) W2 transpose,
//      [8192,10240) router, [10240,10312) fill pad-row arrays ----------------
__global__ __launch_bounds__(256) void prep_k(const float* __restrict__ W1,
                                              const float* __restrict__ W2,
                                              unsigned short* __restrict__ W1bT,
                                              unsigned short* __restrict__ W2bT,
                                              const float* __restrict__ x,
                                              const float* __restrict__ Wr,
                                              const float* __restrict__ br,
                                              int* __restrict__ meta,
                                              int2* __restrict__ top_i,
                                              float2* __restrict__ top_w,
                                              int* __restrict__ tok_of_row,
                                              float* __restrict__ wt_of_row) {
  int id = blockIdx.x;
  if (id < 4096) {                               // W1[e][D][H] -> [e][H][D]
    int rem = id & 511;                          // 16 by x 32 bx per expert
    transpose_body(W1, W1bT, DIM, HID, rem & 31, rem >> 5, id >> 9);
  } else if (id < 8192) {                        // W2[e][H][D] -> [e][D][H]
    int id2 = id - 4096;
    int rem = id2 & 511;                         // 64 by x 8 bx per expert
    transpose_body(W2, W2bT, HID, DIM, rem & 7, rem >> 3, id2 >> 9);
  } else if (id < 10240) {
    router_body(id - 8192, x, Wr, br, meta, top_i, top_w);
  } else {
    int i = (id - 10240) * 256 + threadIdx.x;    // 72*256 == MAXR exactly
    if (i < MAXR) { tok_of_row[i] = 0; wt_of_row[i] = 0.f; }
  }
}

// -------- prefix: padded (x256) offsets ------------------------------------
__global__ void prefix_k(int* __restrict__ meta) {
  if (threadIdx.x == 0) {
    int s = 0;
#pragma unroll
    for (int e = 0; e < NEXP; ++e) {
      meta[16 + e] = s;                          // poff[e]
      s += (meta[e] + 255) & ~255;
    }
    meta[24] = s;                                // poff[8]
    meta[25] = s;                                // total_padded (<= MAXR always)
  }
}

// ---------------- scatter: token -> packed expert row ------------------------
__global__ __launch_bounds__(256) void scatter_k(const int2* __restrict__ top_i,
                                                 const float2* __restrict__ top_w,
                                                 int* __restrict__ meta,
                                                 int* __restrict__ row_of,
                                                 int* __restrict__ tok_of_row,
                                                 float* __restrict__ wt_of_row) {
  int t = blockIdx.x * 256 + threadIdx.x;
  int2  ei = top_i[t];
  float2 w = top_w[t];
  int p = atomicAdd(&meta[8 + ei.x], 1);
  int r = meta[16 + ei.x] + p;
  tok_of_row[r] = t; wt_of_row[r] = w.x; row_of[t * 2] = r;
  p = atomicAdd(&meta[8 + ei.y], 1);
  r = meta[16 + ei.y] + p;
  tok_of_row[r] = t; wt_of_row[r] = w.y; row_of[t * 2 + 1] = r;
}

// ---------------- gather: xg[r][:] = bf16(x[tok[r]][:]) ----------------------
__global__ __launch_bounds__(256) void gather_k(const float* __restrict__ x,
                                                const int* __restrict__ tok_of_row,
                                                const int* __restrict__ meta,
                                                unsigned short* __restrict__ xg) {
  int r = blockIdx.x;
  if (r >= meta[25]) return;
  int t = tok_of_row[r];
  int c = threadIdx.x * 4;
  float4 v = *(const float4*)(x + (size_t)t * DIM + c);
  u16x4 o;
  o[0] = f2bf(v.x); o[1] = f2bf(v.y); o[2] = f2bf(v.z); o[3] = f2bf(v.w);
  *(u16x4*)(xg + (size_t)r * DIM + c) = o;
}

// ---------------- grouped GEMM: r8 loop (BK=64, swizzle) + supertile grid ----
// A: [M][KTOT] bf16 packed rows.  Bt: [E][NTOT][KTOT] bf16 (pre-transposed).
// 128x128 tile, BK=64, 4 waves (2x2), 32KB LDS (A shorts [0,8192), B [8192,16384)).
// LDS region = [128 rows][8 slots x 8 shorts], row stride 128B; slot
// XOR-swizzled by row&7 (write: pre-swizzled global source col; read: XOR slot).
// Per K-tile: sync; 8x gl16; sync; 2 k-steps x {8x ds_read_b128, 16x MFMA}.
// Grid: XCD-chunked; each XCD owns one 4-n-tile supergroup (B-panel 1MB ->
// L2-resident) and walks 4x4 supertiles (A row-group reused x4 from L2).
// EPI 0: h = bf16(gelu(acc+b1))   EPI 1: atomicAdd out[tok] += (acc+b2)*wt
// NOTE: (256,4) is safe at BK=64 (r8: 56 VGPR, no spill, 286us); (256,6)
// spills acc (r7/r9); (256,4)+BK=32 serializes ds_reads (r10).

template <int KTOT, int NTOT, int EPI>
__global__ __launch_bounds__(256, 4) void gemmv12_k(const unsigned short* __restrict__ A,
                                                    const unsigned short* __restrict__ Bt,
                                                    const float* __restrict__ bias,
                                                    const int* __restrict__ meta,
                                                    const float* __restrict__ wt_of_row,
                                                    const int* __restrict__ tok_of_row,
                                                    void* __restrict__ Cout) {
  constexpr int NN  = NTOT / 128;                // 32 or 8
  constexpr int NXB = MAXR / 128;                // 144 row tiles
  constexpr int NWG = NXB * NN;                  // 4608 or 1152, both % 8 == 0
  constexpr int NSR = NXB / 4;                   // 36 row supertiles
  constexpr int NKT = KTOT / 64;                 // 16 or 64
  __shared__ __align__(16) unsigned short lds[16384];   // 32 KiB

  // XCD chunking, then 4x4 supertile decode (row-sub fastest within supertile,
  // row-supertile fastest within the XCD chunk -> B supergroup is L2-pinned)
  int id = ((int)blockIdx.x & 7) * (NWG / 8) + ((int)blockIdx.x >> 3);
  int sid = id >> 4, sub = id & 15;
  int row0 = ((sid % NSR) * 4 + (sub & 3)) * 128;
  int n0   = ((sid / NSR) * 4 + (sub >> 2)) * 128;
  if (row0 >= meta[25]) return;                  // beyond padded total (block-uniform)
  int e = 0;
  while (meta[17 + e] <= row0) ++e;              // tiles never straddle experts
  if (row0 - meta[16 + e] >= meta[e]) return;    // all-pad tile: skip (wt==0 gates EPI1;
                                                 // unwritten hbuf rows are finite garbage
                                                 // multiplied by wt==0 in GEMM2)
  const unsigned short* Bp = Bt + (size_t)e * NTOT * KTOT;

  int tid = threadIdx.x;
  int lane = tid & 63, wid = tid >> 6;
  int wm = wid >> 1, wn = wid & 1;               // 2x2 waves, each owns 64x64 of C

  // staging (T2 write side): issue i covers granules i*256+tid ->
  // row = i*32 + (tid>>3), slot' = tid&7; row&7 = (tid>>3)&7 for all i,
  // so source col-slot s = (tid&7) ^ ((tid>>3)&7) is issue-invariant.
  int s = (tid & 7) ^ ((tid >> 3) & 7);
  const unsigned short* pA = A  + (size_t)(row0 + (tid >> 3)) * KTOT + s * 8;
  const unsigned short* pB = Bp + (size_t)(n0   + (tid >> 3)) * KTOT + s * 8;

  // fragment reads (T2 read side): row = w*64 + i*16 + am; row&7 = am&7;
  // k-step kk, k-group g=lane>>4 -> slot = (kk*4+g) ^ (am&7)
  int am = lane & 15, g = lane >> 4;
  int sw0 = ((0 * 4 + g) ^ (am & 7)) * 8;
  int sw1 = ((1 * 4 + g) ^ (am & 7)) * 8;
  int aRow = (wm * 64 + am) * 64;                // + i*1024 per fragment
  int bRow = 8192 + (wn * 64 + am) * 64;         // + j*1024 per fragment

  f32x4 acc[4][4];
#pragma unroll
  for (int i = 0; i < 4; ++i)
#pragma unroll
    for (int j = 0; j < 4; ++j) acc[i][j] = (f32x4){0.f, 0.f, 0.f, 0.f};

  for (int kt = 0; kt < NKT; ++kt) {
    __syncthreads();                             // prev compute done before overwrite
#pragma unroll
    for (int i = 0; i < 4; ++i) {                // A: rows i*32..i*32+31
      gl16(pA + (size_t)(i * 32) * KTOT + kt * 64, lds + i * 2048 + tid * 8);
      gl16(pB + (size_t)(i * 32) * KTOT + kt * 64, lds + 8192 + i * 2048 + tid * 8);
    }
    __syncthreads();                             // compiler drains vmcnt before barrier
#pragma unroll
    for (int kk = 0; kk < 2; ++kk) {
      int sw = kk ? sw1 : sw0;
      bf16x8 af[4], bv[4];
#pragma unroll
      for (int i = 0; i < 4; ++i)
        af[i] = *(const bf16x8*)(lds + aRow + i * 1024 + sw);
#pragma unroll
      for (int j = 0; j < 4; ++j)
        bv[j] = *(const bf16x8*)(lds + bRow + j * 1024 + sw);
#pragma unroll
      for (int i = 0; i < 4; ++i)
#pragma unroll
        for (int j = 0; j < 4; ++j)
          acc[i][j] = __builtin_amdgcn_mfma_f32_16x16x32_bf16(af[i], bv[j], acc[i][j], 0, 0, 0);
    }
  }

  // epilogue.  C/D: col n = lane&15, row m = (lane>>4)*4 + reg  (validated)
  int rbase = row0 + wm * 64 + (g << 2);
  int nbase = n0 + wn * 64 + am;
  if constexpr (EPI == 0) {
    unsigned short* Hp = (unsigned short*)Cout;
    const float* bp = bias + (size_t)e * NTOT;
#pragma unroll
    for (int i = 0; i < 4; ++i)
#pragma unroll
      for (int j = 0; j < 4; ++j) {
        int n = nbase + j * 16;
        float bv = bp[n];
#pragma unroll
        for (int gg = 0; gg < 4; ++gg) {
          int m = rbase + i * 16 + gg;
          float v = acc[i][j][gg] + bv;
          v = 0.5f * v * (1.f + erff(v * 0.70710678118654752f));   // exact gelu
          Hp[(size_t)m * NTOT + n] = f2bf(v);
        }
      }
  } else {
    float* Op = (float*)Cout;
    const float* bp = bias + (size_t)e * NTOT;
#pragma unroll
    for (int i = 0; i < 4; ++i)
#pragma unroll
      for (int gg = 0; gg < 4; ++gg) {
        int m = rbase + i * 16 + gg;
        float wt = wt_of_row[m];
        if (wt != 0.f) {                         // pad rows excluded (wt exactly 0)
          float* orow = Op + (size_t)tok_of_row[m] * DIM;
#pragma unroll
          for (int j = 0; j < 4; ++j) {
            int n = nbase + j * 16;
            atomicAdd(orow + n, (acc[i][j][gg] + bp[n]) * wt);
          }
        }
      }
  }
}

extern "C" void kernel_launch(void* const* d_in, const int* in_sizes, int n_in,
                              void* d_out, int out_size, void* d_ws, size_t ws_size,
                              hipStream_t stream) {
  const float* x  = (const float*)d_in[0];
  const float* Wr = (const float*)d_in[1];
  const float* br = (const float*)d_in[2];
  const float* W1 = (const float*)d_in[3];
  const float* b1 = (const float*)d_in[4];
  const float* W2 = (const float*)d_in[5];
  const float* b2 = (const float*)d_in[6];
  float* out = (float*)d_out;

  char* base = (char*)d_ws;
  size_t off = 0;
  auto carve = [&](size_t bytes) -> void* {
    void* r = base + off;
    off = (off + bytes + 255) & ~(size_t)255;
    return r;
  };
  int*            meta       = (int*)carve(26 * 4);
  int2*           top_i      = (int2*)carve((size_t)T_TOK * 8);
  float2*         top_w      = (float2*)carve((size_t)T_TOK * 8);
  int*            row_of     = (int*)carve((size_t)T_TOK * 2 * 4);
  int*            tok_of_row = (int*)carve((size_t)MAXR * 4);
  float*          wt_of_row  = (float*)carve((size_t)MAXR * 4);
  unsigned short* xg         = (unsigned short*)carve((size_t)MAXR * DIM * 2);
  unsigned short* W1bT       = (unsigned short*)carve((size_t)NEXP * DIM * HID * 2);
  unsigned short* W2bT       = (unsigned short*)carve((size_t)NEXP * DIM * HID * 2);
  unsigned short* hbuf       = (unsigned short*)carve((size_t)MAXR * HID * 2);
  if (off > ws_size) {
    fprintf(stderr, "kernel_launch: ws_size too small: need %zu have %zu\n", off, ws_size);
    return;
  }

  hipMemsetAsync(meta, 0, 26 * 4, stream);
  hipMemsetAsync(out, 0, (size_t)out_size * 4, stream);   // GEMM2 atomicAdds into out
  hipLaunchKernelGGL(prep_k, dim3(10312), dim3(256), 0, stream,
                     W1, W2, W1bT, W2bT, x, Wr, br, meta, top_i, top_w,
                     tok_of_row, wt_of_row);
  hipLaunchKernelGGL(prefix_k, dim3(1), dim3(64), 0, stream, meta);
  hipLaunchKernelGGL(scatter_k, dim3(T_TOK / 256), dim3(256), 0, stream,
                     top_i, top_w, meta, row_of, tok_of_row, wt_of_row);
  hipLaunchKernelGGL(gather_k, dim3(MAXR), dim3(256), 0, stream, x, tok_of_row, meta, xg);
  hipLaunchKernelGGL((gemmv12_k<DIM, HID, 0>), dim3((MAXR / 128) * (HID / 128)), dim3(256), 0,
                     stream, xg, W1bT, b1, meta, wt_of_row, tok_of_row, (void*)hbuf);
  hipLaunchKernelGGL((gemmv12_k<HID, DIM, 1>), dim3((MAXR / 128) * (DIM / 128)), dim3(256), 0,
                     stream, hbuf, W2bT, b2, meta, wt_of_row, tok_of_row, (void*)out);
}

// Round 13
// 813.449 us; speedup vs baseline: 1.1518x; 1.0016x over previous
//
#include <hip/hip_runtime.h>
#include <cstdio>

// MoE top-2 FFN: B=4,S=2048,D=1024 -> T=8192 tokens; E=8, H=4096, K_TOP=2.
// Round 13: r12 verbatim EXCEPT the weight transpose, rewritten as an
// LDS-staged 128x128-tile transpose with 512B-contiguous reads and
// 256B-contiguous writes (r8/r9 versions both ran 290us at 1TB/s because
// one side was 128B-granular). u32-packed row-pairs, ds_write_b128 in,
// 4x ds_read_b32 out. GEMMs (BK=64+swizzle+supertile), scatter/gather,
// atomic epilogue: unchanged from r12 (814us total, best).

#define T_TOK 8192
#define DIM   1024
#define NEXP  8
#define HID   4096
#define MAXR  18432  // 16384 rows + 8 experts * up-to-255 pad, rounded to 256

typedef float          f32x4   __attribute__((ext_vector_type(4)));
typedef short          bf16x8  __attribute__((ext_vector_type(8)));
typedef unsigned short u16x8   __attribute__((ext_vector_type(8)));
typedef unsigned short u16x4   __attribute__((ext_vector_type(4)));

static __device__ __forceinline__ unsigned short f2bf(float f) {
  unsigned int u = __builtin_bit_cast(unsigned int, f);
  u = (u + 0x7FFFu + ((u >> 16) & 1u)) >> 16;   // round-nearest-even (finite inputs)
  return (unsigned short)u;
}

// async global->LDS, 16B per lane; LDS dest = wave-uniform base + lane*16
static __device__ __forceinline__ void gl16(const void* g, void* l) {
  __builtin_amdgcn_global_load_lds(
      (const __attribute__((address_space(1))) unsigned int*)g,
      (__attribute__((address_space(3))) unsigned int*)l,
      16, 0, 0);
}

// ---------------- transpose + fp32->bf16, LDS-staged 128x128 tile ------------
// W[e][R][C] fp32 -> WT[e][C][R] bf16.
// Phase 1: lanes 0-31 read one full 512B row (float4 each); rows 2p and 2p+1
//   packed column-wise into u32 (hi=odd row); one ds_write_b128 per unit to
//   tl[p][c..c+3] (stride 132 u32 -> 16B-aligned).
// Phase 2: thread reads 4 u32 (rows rg*8..rg*8+7 of col c), unpacks to u16x8,
//   stores; lanes 0-15 cover rg 0..15 of one col -> 256B-contiguous output.
static __device__ __forceinline__ void transpose_body(const float* __restrict__ W,
                                                      unsigned short* __restrict__ WT,
                                                      int R, int C, int bx, int by, int e,
                                                      unsigned int* tl) {
  int t = threadIdx.x;
  int r0 = by * 128, c0 = bx * 128;
  const float* src = W + (size_t)e * R * C + (size_t)r0 * C + c0;
  int cg = t & 31, ph = t >> 5;                  // col-group (x4 floats), p-high
  int c4 = cg * 4;
#pragma unroll
  for (int u = 0; u < 8; ++u) {
    int p = u * 8 + ph;                          // row-pair 0..63
    float4 f0 = *(const float4*)(src + (size_t)(2 * p) * C + c4);
    float4 f1 = *(const float4*)(src + (size_t)(2 * p + 1) * C + c4);
    unsigned int v0 = ((unsigned)f2bf(f1.x) << 16) | f2bf(f0.x);
    unsigned int v1 = ((unsigned)f2bf(f1.y) << 16) | f2bf(f0.y);
    unsigned int v2 = ((unsigned)f2bf(f1.z) << 16) | f2bf(f0.z);
    unsigned int v3 = ((unsigned)f2bf(f1.w) << 16) | f2bf(f0.w);
    *(uint4*)(tl + p * 132 + c4) = make_uint4(v0, v1, v2, v3);
  }
  __syncthreads();
  int rg = t & 15, ch = t >> 4;                  // row-group (x8 rows), col-high
  unsigned short* dst = WT + (size_t)e * R * C + (size_t)c0 * R + r0 + rg * 8;
#pragma unroll
  for (int u = 0; u < 8; ++u) {
    int c = ch + u * 16;
    u16x8 o;
#pragma unroll
    for (int j = 0; j < 4; ++j) {
      unsigned int v = tl[(rg * 4 + j) * 132 + c];
      o[2 * j]     = (unsigned short)(v & 0xffff);
      o[2 * j + 1] = (unsigned short)(v >> 16);
    }
    *(u16x8*)(dst + (size_t)c * R) = o;
  }
}

static __device__ __forceinline__ void router_body(int blk, const float* __restrict__ x,
                                                   const float* __restrict__ Wr,
                                                   const float* __restrict__ br,
                                                   int* __restrict__ meta,
                                                   int2* __restrict__ top_i,
                                                   float2* __restrict__ top_w) {
  int lane = threadIdx.x & 63;
  int wid  = threadIdx.x >> 6;
  int t = blk * 4 + wid;
  const float* xp = x + (size_t)t * DIM + lane * 16;
  float acc[NEXP];
#pragma unroll
  for (int e = 0; e < NEXP; ++e) acc[e] = 0.f;
#pragma unroll
  for (int j = 0; j < 16; j += 4) {
    float4 xv = *(const float4*)(xp + j);
    const float* wp = Wr + (size_t)(lane * 16 + j) * NEXP;
#pragma unroll
    for (int jj = 0; jj < 4; ++jj) {
      float xs = jj == 0 ? xv.x : jj == 1 ? xv.y : jj == 2 ? xv.z : xv.w;
      float4 w0 = *(const float4*)(wp + jj * NEXP);
      float4 w1 = *(const float4*)(wp + jj * NEXP + 4);
      acc[0] += xs * w0.x; acc[1] += xs * w0.y; acc[2] += xs * w0.z; acc[3] += xs * w0.w;
      acc[4] += xs * w1.x; acc[5] += xs * w1.y; acc[6] += xs * w1.z; acc[7] += xs * w1.w;
    }
  }
#pragma unroll
  for (int off = 32; off > 0; off >>= 1) {
#pragma unroll
    for (int e = 0; e < NEXP; ++e) acc[e] += __shfl_xor(acc[e], off);
  }
  if (lane == 0) {
    float l[NEXP];
#pragma unroll
    for (int e = 0; e < NEXP; ++e) l[e] = acc[e] + br[e];
    int e1 = 0;
#pragma unroll
    for (int e = 1; e < NEXP; ++e) if (l[e] > l[e1]) e1 = e;      // ties -> lower idx
    int e2 = (e1 == 0) ? 1 : 0;
#pragma unroll
    for (int e = 0; e < NEXP; ++e) if (e != e1 && l[e] > l[e2]) e2 = e;
    float g  = expf(l[e2] - l[e1]);              // softmax over top-2 == renorm of full softmax
    float w1 = 1.f / (1.f + g);
    top_i[t] = make_int2(e1, e2);
    top_w[t] = make_float2(w1, 1.f - w1);
    atomicAdd(&meta[e1], 1);
    atomicAdd(&meta[e2], 1);
  }
}

// ---- fused prep: [0,2048) W1 transpose, [2048,4096) W2 transpose,
//      [4096,6144) router, [6144,6216) fill pad-row arrays -------------------
__global__ __launch_bounds__(256) void prep_k(const float* __restrict__ W1,
                                              const float* __restrict__ W2,
                                              unsigned short* __restrict__ W1bT,
                                              unsigned short* __restrict__ W2bT,
                                              const float* __restrict__ x,
                                              const float* __restrict__ Wr,
                                              const float* __restrict__ br,
                                              int* __restrict__ meta,
                                              int2* __restrict__ top_i,
                                              float2* __restrict__ top_w,
                                              int* __restrict__ tok_of_row,
                                              float* __restrict__ wt_of_row) {
  __shared__ __align__(16) unsigned int tl[64 * 132];   // 33792 B
  int id = blockIdx.x;
  if (id < 2048) {                               // W1[e][D][H] -> [e][H][D]
    int rem = id & 255;                          // 8 by x 32 bx per expert
    transpose_body(W1, W1bT, DIM, HID, rem & 31, rem >> 5, id >> 8, tl);
  } else if (id < 4096) {                        // W2[e][H][D] -> [e][D][H]
    int id2 = id - 2048;
    int rem = id2 & 255;                         // 32 by x 8 bx per expert
    transpose_body(W2, W2bT, HID, DIM, rem & 7, rem >> 3, id2 >> 8, tl);
  } else if (id < 6144) {
    router_body(id - 4096, x, Wr, br, meta, top_i, top_w);
  } else {
    int i = (id - 6144) * 256 + threadIdx.x;     // 72*256 == MAXR exactly
    if (i < MAXR) { tok_of_row[i] = 0; wt_of_row[i] = 0.f; }
  }
}

// -------- prefix: padded (x256) offsets ------------------------------------
__global__ void prefix_k(int* __restrict__ meta) {
  if (threadIdx.x == 0) {
    int s = 0;
#pragma unroll
    for (int e = 0; e < NEXP; ++e) {
      meta[16 + e] = s;                          // poff[e]
      s += (meta[e] + 255) & ~255;
    }
    meta[24] = s;                                // poff[8]
    meta[25] = s;                                // total_padded (<= MAXR always)
  }
}

// ---------------- scatter: token -> packed expert row ------------------------
__global__ __launch_bounds__(256) void scatter_k(const int2* __restrict__ top_i,
                                                 const float2* __restrict__ top_w,
                                                 int* __restrict__ meta,
                                                 int* __restrict__ row_of,
                                                 int* __restrict__ tok_of_row,
                                                 float* __restrict__ wt_of_row) {
  int t = blockIdx.x * 256 + threadIdx.x;
  int2  ei = top_i[t];
  float2 w = top_w[t];
  int p = atomicAdd(&meta[8 + ei.x], 1);
  int r = meta[16 + ei.x] + p;
  tok_of_row[r] = t; wt_of_row[r] = w.x; row_of[t * 2] = r;
  p = atomicAdd(&meta[8 + ei.y], 1);
  r = meta[16 + ei.y] + p;
  tok_of_row[r] = t; wt_of_row[r] = w.y; row_of[t * 2 + 1] = r;
}

// ---------------- gather: xg[r][:] = bf16(x[tok[r]][:]) ----------------------
__global__ __launch_bounds__(256) void gather_k(const float* __restrict__ x,
                                                const int* __restrict__ tok_of_row,
                                                const int* __restrict__ meta,
                                                unsigned short* __restrict__ xg) {
  int r = blockIdx.x;
  if (r >= meta[25]) return;
  int t = tok_of_row[r];
  int c = threadIdx.x * 4;
  float4 v = *(const float4*)(x + (size_t)t * DIM + c);
  u16x4 o;
  o[0] = f2bf(v.x); o[1] = f2bf(v.y); o[2] = f2bf(v.z); o[3] = f2bf(v.w);
  *(u16x4*)(xg + (size_t)r * DIM + c) = o;
}

// ---------------- grouped GEMM: r8 loop (BK=64, swizzle) + supertile grid ----
// (verbatim from r12: 814us-total best config)

template <int KTOT, int NTOT, int EPI>
__global__ __launch_bounds__(256, 4) void gemmv13_k(const unsigned short* __restrict__ A,
                                                    const unsigned short* __restrict__ Bt,
                                                    const float* __restrict__ bias,
                                                    const int* __restrict__ meta,
                                                    const float* __restrict__ wt_of_row,
                                                    const int* __restrict__ tok_of_row,
                                                    void* __restrict__ Cout) {
  constexpr int NN  = NTOT / 128;                // 32 or 8
  constexpr int NXB = MAXR / 128;                // 144 row tiles
  constexpr int NWG = NXB * NN;                  // 4608 or 1152, both % 8 == 0
  constexpr int NSR = NXB / 4;                   // 36 row supertiles
  constexpr int NKT = KTOT / 64;                 // 16 or 64
  __shared__ __align__(16) unsigned short lds[16384];   // 32 KiB

  // XCD chunking, then 4x4 supertile decode (row-sub fastest within supertile)
  int id = ((int)blockIdx.x & 7) * (NWG / 8) + ((int)blockIdx.x >> 3);
  int sid = id >> 4, sub = id & 15;
  int row0 = ((sid % NSR) * 4 + (sub & 3)) * 128;
  int n0   = ((sid / NSR) * 4 + (sub >> 2)) * 128;
  if (row0 >= meta[25]) return;                  // beyond padded total (block-uniform)
  int e = 0;
  while (meta[17 + e] <= row0) ++e;              // tiles never straddle experts
  if (row0 - meta[16 + e] >= meta[e]) return;    // all-pad tile: skip (wt==0 gates EPI1)
  const unsigned short* Bp = Bt + (size_t)e * NTOT * KTOT;

  int tid = threadIdx.x;
  int lane = tid & 63, wid = tid >> 6;
  int wm = wid >> 1, wn = wid & 1;               // 2x2 waves, each owns 64x64 of C

  // staging (T2 write side): source col-slot s = (tid&7) ^ ((tid>>3)&7)
  int s = (tid & 7) ^ ((tid >> 3) & 7);
  const unsigned short* pA = A  + (size_t)(row0 + (tid >> 3)) * KTOT + s * 8;
  const unsigned short* pB = Bp + (size_t)(n0   + (tid >> 3)) * KTOT + s * 8;

  // fragment reads (T2 read side): slot = (kk*4+g) ^ (am&7)
  int am = lane & 15, g = lane >> 4;
  int sw0 = ((0 * 4 + g) ^ (am & 7)) * 8;
  int sw1 = ((1 * 4 + g) ^ (am & 7)) * 8;
  int aRow = (wm * 64 + am) * 64;                // + i*1024 per fragment
  int bRow = 8192 + (wn * 64 + am) * 64;         // + j*1024 per fragment

  f32x4 acc[4][4];
#pragma unroll
  for (int i = 0; i < 4; ++i)
#pragma unroll
    for (int j = 0; j < 4; ++j) acc[i][j] = (f32x4){0.f, 0.f, 0.f, 0.f};

  for (int kt = 0; kt < NKT; ++kt) {
    __syncthreads();                             // prev compute done before overwrite
#pragma unroll
    for (int i = 0; i < 4; ++i) {                // A: rows i*32..i*32+31
      gl16(pA + (size_t)(i * 32) * KTOT + kt * 64, lds + i * 2048 + tid * 8);
      gl16(pB + (size_t)(i * 32) * KTOT + kt * 64, lds + 8192 + i * 2048 + tid * 8);
    }
    __syncthreads();                             // compiler drains vmcnt before barrier
#pragma unroll
    for (int kk = 0; kk < 2; ++kk) {
      int sw = kk ? sw1 : sw0;
      bf16x8 af[4], bv[4];
#pragma unroll
      for (int i = 0; i < 4; ++i)
        af[i] = *(const bf16x8*)(lds + aRow + i * 1024 + sw);
#pragma unroll
      for (int j = 0; j < 4; ++j)
        bv[j] = *(const bf16x8*)(lds + bRow + j * 1024 + sw);
#pragma unroll
      for (int i = 0; i < 4; ++i)
#pragma unroll
        for (int j = 0; j < 4; ++j)
          acc[i][j] = __builtin_amdgcn_mfma_f32_16x16x32_bf16(af[i], bv[j], acc[i][j], 0, 0, 0);
    }
  }

  // epilogue.  C/D: col n = lane&15, row m = (lane>>4)*4 + reg  (validated)
  int rbase = row0 + wm * 64 + (g << 2);
  int nbase = n0 + wn * 64 + am;
  if constexpr (EPI == 0) {
    unsigned short* Hp = (unsigned short*)Cout;
    const float* bp = bias + (size_t)e * NTOT;
#pragma unroll
    for (int i = 0; i < 4; ++i)
#pragma unroll
      for (int j = 0; j < 4; ++j) {
        int n = nbase + j * 16;
        float bv = bp[n];
#pragma unroll
        for (int gg = 0; gg < 4; ++gg) {
          int m = rbase + i * 16 + gg;
          float v = acc[i][j][gg] + bv;
          v = 0.5f * v * (1.f + erff(v * 0.70710678118654752f));   // exact gelu
          Hp[(size_t)m * NTOT + n] = f2bf(v);
        }
      }
  } else {
    float* Op = (float*)Cout;
    const float* bp = bias + (size_t)e * NTOT;
#pragma unroll
    for (int i = 0; i < 4; ++i)
#pragma unroll
      for (int gg = 0; gg < 4; ++gg) {
        int m = rbase + i * 16 + gg;
        float wt = wt_of_row[m];
        if (wt != 0.f) {                         // pad rows excluded (wt exactly 0)
          float* orow = Op + (size_t)tok_of_row[m] * DIM;
#pragma unroll
          for (int j = 0; j < 4; ++j) {
            int n = nbase + j * 16;
            atomicAdd(orow + n, (acc[i][j][gg] + bp[n]) * wt);
          }
        }
      }
  }
}

extern "C" void kernel_launch(void* const* d_in, const int* in_sizes, int n_in,
                              void* d_out, int out_size, void* d_ws, size_t ws_size,
                              hipStream_t stream) {
  const float* x  = (const float*)d_in[0];
  const float* Wr = (const float*)d_in[1];
  const float* br = (const float*)d_in[2];
  const float* W1 = (const float*)d_in[3];
  const float* b1 = (const float*)d_in[4];
  const float* W2 = (const float*)d_in[5];
  const float* b2 = (const float*)d_in[6];
  float* out = (float*)d_out;

  char* base = (char*)d_ws;
  size_t off = 0;
  auto carve = [&](size_t bytes) -> void* {
    void* r = base + off;
    off = (off + bytes + 255) & ~(size_t)255;
    return r;
  };
  int*            meta       = (int*)carve(26 * 4);
  int2*           top_i      = (int2*)carve((size_t)T_TOK * 8);
  float2*         top_w      = (float2*)carve((size_t)T_TOK * 8);
  int*            row_of     = (int*)carve((size_t)T_TOK * 2 * 4);
  int*            tok_of_row = (int*)carve((size_t)MAXR * 4);
  float*          wt_of_row  = (float*)carve((size_t)MAXR * 4);
  unsigned short* xg         = (unsigned short*)carve((size_t)MAXR * DIM * 2);
  unsigned short* W1bT       = (unsigned short*)carve((size_t)NEXP * DIM * HID * 2);
  unsigned short* W2bT       = (unsigned short*)carve((size_t)NEXP * DIM * HID * 2);
  unsigned short* hbuf       = (unsigned short*)carve((size_t)MAXR * HID * 2);
  if (off > ws_size) {
    fprintf(stderr, "kernel_launch: ws_size too small: need %zu have %zu\n", off, ws_size);
    return;
  }

  hipMemsetAsync(meta, 0, 26 * 4, stream);
  hipMemsetAsync(out, 0, (size_t)out_size * 4, stream);   // GEMM2 atomicAdds into out
  hipLaunchKernelGGL(prep_k, dim3(6216), dim3(256), 0, stream,
                     W1, W2, W1bT, W2bT, x, Wr, br, meta, top_i, top_w,
                     tok_of_row, wt_of_row);
  hipLaunchKernelGGL(prefix_k, dim3(1), dim3(64), 0, stream, meta);
  hipLaunchKernelGGL(scatter_k, dim3(T_TOK / 256), dim3(256), 0, stream,
                     top_i, top_w, meta, row_of, tok_of_row, wt_of_row);
  hipLaunchKernelGGL(gather_k, dim3(MAXR), dim3(256), 0, stream, x, tok_of_row, meta, xg);
  hipLaunchKernelGGL((gemmv13_k<DIM, HID, 0>), dim3((MAXR / 128) * (HID / 128)), dim3(256), 0,
                     stream, xg, W1bT, b1, meta, wt_of_row, tok_of_row, (void*)hbuf);
  hipLaunchKernelGGL((gemmv13_k<HID, DIM, 1>), dim3((MAXR / 128) * (DIM / 128)), dim3(256), 0,
                     stream, hbuf, W2bT, b2, meta, wt_of_row, tok_of_row, (void*)out);
}